// Round 3
// baseline (169.585 us; speedup 1.0000x reference)
//
#include <hip/hip_runtime.h>
#include <math.h>

// ---------------------------------------------------------------------------
// RopeAttentionModel reduced form:
//   x[s,:] = c_s * ones(HID)  =>  q/k/v are rank-1: c_s * colsum(W)
//   scores[s,hg,k] = c_s*c_k * D[hg, s-k] / sqrt(128)
//   D[hg,d] = sum_j P[hg,j]*cos(d*f_j) - Q[hg,j]*sin(d*f_j)   (f64)
//   attn out scalar alpha[s,hg] = softmax-weighted mean of c_k
//   final = A[S,32] @ M[32,4096],  M[hg,:] = Sv[h] . Wo[hg*128:+128, :]
// ---------------------------------------------------------------------------

#define HID 4096
#define NQH 32
#define NKVH 8
#define HD 128
#define RSQRT_HD 0.08838834764831845f
#define SQRT_HD  11.313708498984761f

// 16-row column-sum tile: 2 batches of 8 in-flight float4 loads.
__device__ __forceinline__ void colsum16(const float* __restrict__ W,
                                         float* __restrict__ Sd,
                                         int cols4, int c4, int r0) {
    const float4* b = reinterpret_cast<const float4*>(W);
    float ax = 0.f, ay = 0.f, az = 0.f, aw = 0.f;
#pragma unroll
    for (int bb = 0; bb < 2; ++bb) {
        size_t p = (size_t)(r0 + bb * 8) * cols4 + c4;
        float4 t0 = b[p];
        float4 t1 = b[p + 1 * (size_t)cols4];
        float4 t2 = b[p + 2 * (size_t)cols4];
        float4 t3 = b[p + 3 * (size_t)cols4];
        float4 t4 = b[p + 4 * (size_t)cols4];
        float4 t5 = b[p + 5 * (size_t)cols4];
        float4 t6 = b[p + 6 * (size_t)cols4];
        float4 t7 = b[p + 7 * (size_t)cols4];
        ax += ((t0.x + t1.x) + (t2.x + t3.x)) + ((t4.x + t5.x) + (t6.x + t7.x));
        ay += ((t0.y + t1.y) + (t2.y + t3.y)) + ((t4.y + t5.y) + (t6.y + t7.y));
        az += ((t0.z + t1.z) + (t2.z + t3.z)) + ((t4.z + t5.z) + (t6.z + t7.z));
        aw += ((t0.w + t1.w) + (t2.w + t3.w)) + ((t4.w + t5.w) + (t6.w + t7.w));
    }
    int c = c4 * 4;
    atomicAdd(&Sd[c + 0], ax);
    atomicAdd(&Sd[c + 1], ay);
    atomicAdd(&Sd[c + 2], az);
    atomicAdd(&Sd[c + 3], aw);
}

// ---- Sv = colsum(Wv): must run before k_big (k_m part consumes it) ----
__global__ __launch_bounds__(256) void k_sv(const float* __restrict__ Wv,
                                            float* __restrict__ Sv) {
    colsum16(Wv, Sv, NKVH * HD / 4, threadIdx.x, blockIdx.x * 16);
}

// ---- fused streaming dispatch: trig table + Wq/Wk colsums + M = Sv.Wo ----
__global__ __launch_bounds__(256) void k_big(
        const int* __restrict__ ids,
        const float* __restrict__ Wq, const float* __restrict__ Wk,
        const float* __restrict__ Wo, const float* __restrict__ Sv,
        float* __restrict__ Sq, float* __restrict__ Sk, float* __restrict__ cp,
        double* __restrict__ Tc, double* __restrict__ Ts, float* __restrict__ M,
        int S) {
    int t = blockIdx.x;
    int tid = threadIdx.x;
    int nxb = S >> 8;
    int trigT = 64 * nxb;
    if (t < trigT) {
        // trig tiles first: long-latency f64 sincos starts early
        int j = t / nxb, xb = t - j * nxb;
        int dlt = xb * 256 + tid;
        double f = (double)(float)(1.0 / pow(10000.0, (double)j / 64.0));
        double sv, cv;
        sincos((double)dlt * f, &sv, &cv);
        Tc[(size_t)j * S + dlt] = cv;
        Ts[(size_t)j * S + dlt] = sv;
        if (j == 0) cp[dlt] = (float)ids[dlt] * RSQRT_HD;
    } else if (t < trigT + 1024) {
        int u = t - trigT;
        colsum16(Wq, Sq, NQH * HD / 4, (u & 3) * 256 + tid, (u >> 2) * 16);
    } else if (t < trigT + 1280) {
        int y = t - trigT - 1024;
        colsum16(Wk, Sk, NKVH * HD / 4, tid, y * 16);
    } else {
        // M[hg, :] += Sv[h, d0:d0+16] . Wo[hg*128+d0 : +16, :]
        int u = t - trigT - 1280;
        int hg = u >> 5, x = (u >> 3) & 3, z = u & 7;
        int h = hg >> 2, d0 = z * 16;
        int i4 = x * 256 + tid;
        const float4* b = reinterpret_cast<const float4*>(Wo);
        float ax = 0.f, ay = 0.f, az = 0.f, aw = 0.f;
#pragma unroll
        for (int bb = 0; bb < 2; ++bb) {
            int dd = d0 + bb * 8;
            size_t p = (size_t)(hg * HD + dd) * (HID / 4) + i4;
            float s0 = Sv[h * HD + dd + 0], s1 = Sv[h * HD + dd + 1];
            float s2 = Sv[h * HD + dd + 2], s3 = Sv[h * HD + dd + 3];
            float s4 = Sv[h * HD + dd + 4], s5 = Sv[h * HD + dd + 5];
            float s6 = Sv[h * HD + dd + 6], s7 = Sv[h * HD + dd + 7];
            float4 t0 = b[p];
            float4 t1 = b[p + 1 * (size_t)(HID / 4)];
            float4 t2 = b[p + 2 * (size_t)(HID / 4)];
            float4 t3 = b[p + 3 * (size_t)(HID / 4)];
            float4 t4 = b[p + 4 * (size_t)(HID / 4)];
            float4 t5 = b[p + 5 * (size_t)(HID / 4)];
            float4 t6 = b[p + 6 * (size_t)(HID / 4)];
            float4 t7 = b[p + 7 * (size_t)(HID / 4)];
            ax += ((s0 * t0.x + s1 * t1.x) + (s2 * t2.x + s3 * t3.x)) +
                  ((s4 * t4.x + s5 * t5.x) + (s6 * t6.x + s7 * t7.x));
            ay += ((s0 * t0.y + s1 * t1.y) + (s2 * t2.y + s3 * t3.y)) +
                  ((s4 * t4.y + s5 * t5.y) + (s6 * t6.y + s7 * t7.y));
            az += ((s0 * t0.z + s1 * t1.z) + (s2 * t2.z + s3 * t3.z)) +
                  ((s4 * t4.z + s5 * t5.z) + (s6 * t6.z + s7 * t7.z));
            aw += ((s0 * t0.w + s1 * t1.w) + (s2 * t2.w + s3 * t3.w)) +
                  ((s4 * t4.w + s5 * t5.w) + (s6 * t6.w + s7 * t7.w));
        }
        int c = i4 * 4;
        atomicAdd(&M[(size_t)hg * HID + c + 0], ax);
        atomicAdd(&M[(size_t)hg * HID + c + 1], ay);
        atomicAdd(&M[(size_t)hg * HID + c + 2], az);
        atomicAdd(&M[(size_t)hg * HID + c + 3], aw);
    }
}

// ---- D table: [32][S], f64 accumulation over the shared trig table ----
__global__ void k_dtab(const float* __restrict__ Sq, const float* __restrict__ Sk,
                       const double* __restrict__ Tc, const double* __restrict__ Ts,
                       float* __restrict__ D, int S) {
    __shared__ double p[64], q[64];
    int hg = blockIdx.y, h = hg >> 2;
    int tid = threadIdx.x;
    if (tid < 64) {
        double a1 = Sq[hg * HD + tid], a2 = Sq[hg * HD + tid + 64];
        double b1 = Sk[h * HD + tid],  b2 = Sk[h * HD + tid + 64];
        p[tid] = a1 * b1 + a2 * b2;
        q[tid] = a2 * b1 - a1 * b2;
    }
    __syncthreads();
    int dlt = blockIdx.x * 256 + tid;
    double acc = 0.0;
    for (int j = 0; j < 64; ++j)
        acc += p[j] * Tc[(size_t)j * S + dlt] - q[j] * Ts[(size_t)j * S + dlt];
    D[(size_t)hg * S + dlt] = (float)acc;
}

// ---- alpha[s][hg]: one wave per (s,hg), single-pass online softmax ----
__global__ __launch_bounds__(256) void k_alpha(
        const int* __restrict__ ids, const float* __restrict__ cp,
        const float* __restrict__ D, float* __restrict__ A, int S) {
    int w = blockIdx.x * 4 + (threadIdx.x >> 6);
    int lane = threadIdx.x & 63;
    int s = S - 1 - (w >> 5);              // long rows dispatched first
    int hg = w & 31;
    float cs = (float)ids[s];
    const float* Drow = D + (size_t)hg * S;
    const float* cps = cp + s;             // cps[-dlt] = cp[s-dlt] = cp[k]

    float m = -INFINITY, se = 0.f, sp = 0.f;
    int n = s + 1;
    int nFull = n >> 8;                    // full 256-element chunks
    for (int it = 0; it < nFull; ++it) {
        int d0 = it * 256 + lane * 4;
        float4 dv = *reinterpret_cast<const float4*>(Drow + d0);
        float c0 = cps[-(d0 + 0)], c1 = cps[-(d0 + 1)];
        float c2 = cps[-(d0 + 2)], c3 = cps[-(d0 + 3)];
        float z0 = cs * (c0 * dv.x), z1 = cs * (c1 * dv.y);
        float z2 = cs * (c2 * dv.z), z3 = cs * (c3 * dv.w);
        float zc = fmaxf(fmaxf(z0, z1), fmaxf(z2, z3));
        float r = __expf(fminf(m - zc, 0.f));   // branchless deferred rescale
        se *= r; sp *= r; m = fmaxf(m, zc);
        float e0 = __expf(z0 - m), e1 = __expf(z1 - m);
        float e2 = __expf(z2 - m), e3 = __expf(z3 - m);
        se += (e0 + e1) + (e2 + e3);
        sp += e0 * c0 + e1 * c1 + e2 * c2 + e3 * c3;
    }
    if (n & 255) {                          // masked tail chunk
        int d0 = nFull * 256 + lane * 4;
        float4 dv = *reinterpret_cast<const float4*>(Drow + d0); // padded OOB ok
        float c0 = cps[-(d0 + 0)], c1 = cps[-(d0 + 1)];
        float c2 = cps[-(d0 + 2)], c3 = cps[-(d0 + 3)];
        float z0 = (d0 + 0 < n) ? cs * (c0 * dv.x) : -INFINITY;
        float z1 = (d0 + 1 < n) ? cs * (c1 * dv.y) : -INFINITY;
        float z2 = (d0 + 2 < n) ? cs * (c2 * dv.z) : -INFINITY;
        float z3 = (d0 + 3 < n) ? cs * (c3 * dv.w) : -INFINITY;
        float zc = fmaxf(fmaxf(z0, z1), fmaxf(z2, z3));
        float r = __expf(fminf(m - zc, 0.f));   // min kills -inf-(-inf)=NaN
        se *= r; sp *= r; m = fmaxf(m, zc);
        float mm = fmaxf(m, -1e30f);            // keep finite for lanes w/o data
        float e0 = __expf(z0 - mm), e1 = __expf(z1 - mm);
        float e2 = __expf(z2 - mm), e3 = __expf(z3 - mm);
        se += (e0 + e1) + (e2 + e3);
        sp += e0 * c0 + e1 * c1 + e2 * c2 + e3 * c3;
    }
    // cross-lane merge of (m, se, sp)
    for (int o = 32; o; o >>= 1) {
        float mo = __shfl_xor(m, o);
        float so = __shfl_xor(se, o);
        float po = __shfl_xor(sp, o);
        float M = fmaxf(m, mo);
        float e1 = __expf(fminf(m - M, 0.f));
        float e2 = __expf(fminf(mo - M, 0.f));
        se = se * e1 + so * e2;
        sp = sp * e1 + po * e2;
        m = M;
    }
    if (lane == 0) A[(size_t)s * NQH + hg] = SQRT_HD * sp / se;
}

// ---- final = A @ M, tiled 16 rows x 256 cols per block ----
__global__ void k_out(const float* __restrict__ A, const float* __restrict__ M,
                      float* __restrict__ out, int S) {
    __shared__ float a[512];
    int tid = threadIdx.x;
    int s0 = blockIdx.y * 16;
    a[tid] = A[(size_t)s0 * NQH + tid];
    a[tid + 256] = A[(size_t)s0 * NQH + tid + 256];
    __syncthreads();
    int i = blockIdx.x * 256 + tid;
    float acc[16];
#pragma unroll
    for (int r = 0; r < 16; ++r) acc[r] = 0.f;
    for (int hg = 0; hg < NQH; ++hg) {
        float mv = M[(size_t)hg * HID + i];
#pragma unroll
        for (int r = 0; r < 16; ++r) acc[r] += a[r * NQH + hg] * mv;
    }
#pragma unroll
    for (int r = 0; r < 16; ++r)
        out[(size_t)(s0 + r) * HID + i] = acc[r];
}

extern "C" void kernel_launch(void* const* d_in, const int* in_sizes, int n_in,
                              void* d_out, int out_size, void* d_ws, size_t ws_size,
                              hipStream_t stream) {
    const int*   ids = (const int*)d_in[0];
    const float* Wq  = (const float*)d_in[2];
    const float* Wk  = (const float*)d_in[3];
    const float* Wv  = (const float*)d_in[4];
    const float* Wo  = (const float*)d_in[5];
    float* out = (float*)d_out;
    const int S = in_sizes[0];                      // B=1, S=2048

    // ws layout: [Sq 4096][Sk 1024][Sv 1024][M 131072][D 32S][cp S][A 32S][Tc/Ts f64]
    // cp must sit right after D: k_alpha's negative cps[] reads land in D,
    // and float4 over-reads past D's end land in cp (masked lanes).
    float* ws = (float*)d_ws;
    float* Sq = ws;
    float* Sk = Sq + HID;
    float* Sv = Sk + NKVH * HD;
    float* M  = Sv + NKVH * HD;
    float* D  = M + (size_t)NQH * HID;
    float* cp = D + (size_t)NQH * S;
    float* A  = cp + S;
    double* Tc = (double*)(A + (size_t)NQH * S);
    double* Ts = Tc + (size_t)64 * S;

    // zero the atomic-accumulated buffers (Sq,Sk,Sv,M contiguous)
    hipMemsetAsync(Sq, 0, (size_t)(HID + 2 * NKVH * HD + NQH * HID) * sizeof(float), stream);

    k_sv<<<256, 256, 0, stream>>>(Wv, Sv);
    int nxb = S >> 8;
    k_big<<<64 * nxb + 1024 + 256 + 1024, 256, 0, stream>>>(
        ids, Wq, Wk, Wo, Sv, Sq, Sk, cp, Tc, Ts, M, S);
    k_dtab<<<dim3(S / 256, NQH), 256, 0, stream>>>(Sq, Sk, Tc, Ts, D, S);
    k_alpha<<<S * 8, 256, 0, stream>>>(ids, cp, D, A, S);
    k_out<<<dim3(HID / 256, S / 16), 256, 0, stream>>>(A, M, out, S);
}

// Round 4
// 104.503 us; speedup vs baseline: 1.6228x; 1.6228x over previous
//
#include <hip/hip_runtime.h>
#include <math.h>

// ---------------------------------------------------------------------------
// RopeAttentionModel reduced form:
//   x[s,:] = c_s * ones(HID)  =>  q/k/v are rank-1: c_s * colsum(W)
//   scores[s,hg,k] = c_s*c_k * D[hg, s-k] / sqrt(128)
//   D[hg,d] = sum_j P[hg,j]*cos(d*f_j) - Q[hg,j]*sin(d*f_j)   (f64)
//   attn out scalar alpha[s,hg] = softmax-weighted mean of c_k
//   final = A[S,32] @ M[32,4096],  M[hg,:] = Sv[h] . Wo[hg*128:+128, :]
// No atomics anywhere: partial-sum buffers + tiny reduce kernel.
// ---------------------------------------------------------------------------

#define HID 4096
#define NQH 32
#define NKVH 8
#define HD 128
#define CH 64                     // column-sum chunks (64 rows each)
#define RSQRT_HD 0.08838834764831845f
#define SQRT_HD  11.313708498984761f

// partial column sum over 64 rows, 8 batches of 8 in-flight float4 loads
__device__ __forceinline__ void colsum_part(const float* __restrict__ W,
                                            float* __restrict__ P,
                                            int cols4, int c4, int chunk) {
    const float4* b = reinterpret_cast<const float4*>(W);
    float ax = 0.f, ay = 0.f, az = 0.f, aw = 0.f;
#pragma unroll
    for (int bb = 0; bb < 8; ++bb) {
        size_t p = (size_t)(chunk * 64 + bb * 8) * cols4 + c4;
        float4 t0 = b[p];
        float4 t1 = b[p + 1 * (size_t)cols4];
        float4 t2 = b[p + 2 * (size_t)cols4];
        float4 t3 = b[p + 3 * (size_t)cols4];
        float4 t4 = b[p + 4 * (size_t)cols4];
        float4 t5 = b[p + 5 * (size_t)cols4];
        float4 t6 = b[p + 6 * (size_t)cols4];
        float4 t7 = b[p + 7 * (size_t)cols4];
        ax += ((t0.x + t1.x) + (t2.x + t3.x)) + ((t4.x + t5.x) + (t6.x + t7.x));
        ay += ((t0.y + t1.y) + (t2.y + t3.y)) + ((t4.y + t5.y) + (t6.y + t7.y));
        az += ((t0.z + t1.z) + (t2.z + t3.z)) + ((t4.z + t5.z) + (t6.z + t7.z));
        aw += ((t0.w + t1.w) + (t2.w + t3.w)) + ((t4.w + t5.w) + (t6.w + t7.w));
    }
    reinterpret_cast<float4*>(P)[(size_t)chunk * cols4 + c4] =
        make_float4(ax, ay, az, aw);
}

// ---- fused: trig table + Wq/Wk/Wv partial colsums (no deps, no atomics) ----
__global__ __launch_bounds__(256) void k_part(
        const int* __restrict__ ids,
        const float* __restrict__ Wq, const float* __restrict__ Wk,
        const float* __restrict__ Wv,
        float* __restrict__ Pq, float* __restrict__ Pk, float* __restrict__ Pv,
        float* __restrict__ cp, double* __restrict__ Tc, double* __restrict__ Ts,
        int S) {
    int t = blockIdx.x;
    int tid = threadIdx.x;
    int nxb = S >> 8;
    int trigT = 64 * nxb;
    if (t < trigT) {
        int j = t / nxb, xb = t - j * nxb;
        int dlt = xb * 256 + tid;
        double f = (double)(float)(1.0 / pow(10000.0, (double)j / 64.0));
        double sv, cv;
        sincos((double)dlt * f, &sv, &cv);
        Tc[(size_t)j * S + dlt] = cv;
        Ts[(size_t)j * S + dlt] = sv;
        if (j == 0) cp[dlt] = (float)ids[dlt] * RSQRT_HD;
    } else if (t < trigT + 4 * CH) {
        int u = t - trigT;
        colsum_part(Wq, Pq, NQH * HD / 4, (u & 3) * 256 + tid, u >> 2);
    } else if (t < trigT + 5 * CH) {
        colsum_part(Wk, Pk, NKVH * HD / 4, tid, t - trigT - 4 * CH);
    } else {
        colsum_part(Wv, Pv, NKVH * HD / 4, tid, t - trigT - 5 * CH);
    }
}

// ---- reduce partials -> Sq, Sk, Sv (6 blocks, ~1.5 MB of L2 reads) ----
__global__ __launch_bounds__(256) void k_red(
        const float* __restrict__ Pq, const float* __restrict__ Pk,
        const float* __restrict__ Pv, float* __restrict__ Sq,
        float* __restrict__ Sk, float* __restrict__ Sv) {
    int t = blockIdx.x;
    const float* P; float* Sd; int cols4, c4;
    if (t < 4)      { P = Pq; Sd = Sq; cols4 = NQH * HD / 4; c4 = t * 256 + threadIdx.x; }
    else if (t == 4){ P = Pk; Sd = Sk; cols4 = NKVH * HD / 4; c4 = threadIdx.x; }
    else            { P = Pv; Sd = Sv; cols4 = NKVH * HD / 4; c4 = threadIdx.x; }
    const float4* b = reinterpret_cast<const float4*>(P);
    float4 a = make_float4(0.f, 0.f, 0.f, 0.f);
#pragma unroll 8
    for (int c = 0; c < CH; ++c) {
        float4 v = b[(size_t)c * cols4 + c4];
        a.x += v.x; a.y += v.y; a.z += v.z; a.w += v.w;
    }
    reinterpret_cast<float4*>(Sd)[c4] = a;
}

// ---- fused: M = Sv.Wo (plain stores) + D table from trig ----
__global__ __launch_bounds__(256) void k_main(
        const float* __restrict__ Sq, const float* __restrict__ Sk,
        const float* __restrict__ Sv, const float* __restrict__ Wo,
        const double* __restrict__ Tc, const double* __restrict__ Ts,
        float* __restrict__ M, float* __restrict__ D, int S) {
    int t = blockIdx.x;
    int tid = threadIdx.x;
    if (t < 128) {
        // M[hg, :] = sum_d Sv[h,d] * Wo[hg*128+d, :]
        int hg = t >> 2, x = t & 3, h = hg >> 2;
        int i4 = x * 256 + tid;
        const float4* b = reinterpret_cast<const float4*>(Wo);
        float ax = 0.f, ay = 0.f, az = 0.f, aw = 0.f;
        for (int d0 = 0; d0 < HD; d0 += 8) {
            size_t p = (size_t)(hg * HD + d0) * (HID / 4) + i4;
            float s0 = Sv[h * HD + d0 + 0], s1 = Sv[h * HD + d0 + 1];
            float s2 = Sv[h * HD + d0 + 2], s3 = Sv[h * HD + d0 + 3];
            float s4 = Sv[h * HD + d0 + 4], s5 = Sv[h * HD + d0 + 5];
            float s6 = Sv[h * HD + d0 + 6], s7 = Sv[h * HD + d0 + 7];
            float4 t0 = b[p];
            float4 t1 = b[p + 1 * (size_t)(HID / 4)];
            float4 t2 = b[p + 2 * (size_t)(HID / 4)];
            float4 t3 = b[p + 3 * (size_t)(HID / 4)];
            float4 t4 = b[p + 4 * (size_t)(HID / 4)];
            float4 t5 = b[p + 5 * (size_t)(HID / 4)];
            float4 t6 = b[p + 6 * (size_t)(HID / 4)];
            float4 t7 = b[p + 7 * (size_t)(HID / 4)];
            ax += ((s0 * t0.x + s1 * t1.x) + (s2 * t2.x + s3 * t3.x)) +
                  ((s4 * t4.x + s5 * t5.x) + (s6 * t6.x + s7 * t7.x));
            ay += ((s0 * t0.y + s1 * t1.y) + (s2 * t2.y + s3 * t3.y)) +
                  ((s4 * t4.y + s5 * t5.y) + (s6 * t6.y + s7 * t7.y));
            az += ((s0 * t0.z + s1 * t1.z) + (s2 * t2.z + s3 * t3.z)) +
                  ((s4 * t4.z + s5 * t5.z) + (s6 * t6.z + s7 * t7.z));
            aw += ((s0 * t0.w + s1 * t1.w) + (s2 * t2.w + s3 * t3.w)) +
                  ((s4 * t4.w + s5 * t5.w) + (s6 * t6.w + s7 * t7.w));
        }
        reinterpret_cast<float4*>(M)[(size_t)hg * (HID / 4) + i4] =
            make_float4(ax, ay, az, aw);
    } else {
        // D[hg, dlt] = sum_j p[j]*cos - q[j]*sin   (f64)
        __shared__ double p[64], q[64];
        int u = t - 128;
        int nxb = S >> 8;
        int hg = u / nxb, xb = u - hg * nxb, h = hg >> 2;
        if (tid < 64) {
            double a1 = Sq[hg * HD + tid], a2 = Sq[hg * HD + tid + 64];
            double b1 = Sk[h * HD + tid],  b2 = Sk[h * HD + tid + 64];
            p[tid] = a1 * b1 + a2 * b2;
            q[tid] = a2 * b1 - a1 * b2;
        }
        __syncthreads();
        int dlt = xb * 256 + tid;
        const double* tc = Tc + dlt;
        const double* ts = Ts + dlt;
        double acc = 0.0;
#pragma unroll 8
        for (int j = 0; j < 64; ++j)
            acc += p[j] * tc[(size_t)j * S] - q[j] * ts[(size_t)j * S];
        D[(size_t)hg * S + dlt] = (float)acc;
    }
}

// ---- alpha[s][hg]: one wave per (s,hg), single-pass online softmax ----
__global__ __launch_bounds__(256) void k_alpha(
        const int* __restrict__ ids, const float* __restrict__ cp,
        const float* __restrict__ D, float* __restrict__ A, int S) {
    int w = blockIdx.x * 4 + (threadIdx.x >> 6);
    int lane = threadIdx.x & 63;
    int s = S - 1 - (w >> 5);              // long rows dispatched first
    int hg = w & 31;
    float cs = (float)ids[s];
    const float* Drow = D + (size_t)hg * S;
    const float* cps = cp + s;             // cps[-dlt] = cp[s-dlt] = cp[k]

    float m = -INFINITY, se = 0.f, sp = 0.f;
    int n = s + 1;
    int nFull = n >> 8;                    // full 256-element chunks
    for (int it = 0; it < nFull; ++it) {
        int d0 = it * 256 + lane * 4;
        float4 dv = *reinterpret_cast<const float4*>(Drow + d0);
        float c0 = cps[-(d0 + 0)], c1 = cps[-(d0 + 1)];
        float c2 = cps[-(d0 + 2)], c3 = cps[-(d0 + 3)];
        float z0 = cs * (c0 * dv.x), z1 = cs * (c1 * dv.y);
        float z2 = cs * (c2 * dv.z), z3 = cs * (c3 * dv.w);
        float zc = fmaxf(fmaxf(z0, z1), fmaxf(z2, z3));
        if (!__all(zc <= m)) {             // wave-uniform: skip rescale when max holds
            float r = __expf(fminf(m - zc, 0.f));
            se *= r; sp *= r; m = fmaxf(m, zc);
        }
        float e0 = __expf(z0 - m), e1 = __expf(z1 - m);
        float e2 = __expf(z2 - m), e3 = __expf(z3 - m);
        se += (e0 + e1) + (e2 + e3);
        sp += e0 * c0 + e1 * c1 + e2 * c2 + e3 * c3;
    }
    if (n & 255) {                          // masked tail chunk
        int d0 = nFull * 256 + lane * 4;
        float4 dv = *reinterpret_cast<const float4*>(Drow + d0); // pad reads land in cp
        float c0 = cps[-(d0 + 0)], c1 = cps[-(d0 + 1)];
        float c2 = cps[-(d0 + 2)], c3 = cps[-(d0 + 3)];
        float z0 = (d0 + 0 < n) ? cs * (c0 * dv.x) : -INFINITY;
        float z1 = (d0 + 1 < n) ? cs * (c1 * dv.y) : -INFINITY;
        float z2 = (d0 + 2 < n) ? cs * (c2 * dv.z) : -INFINITY;
        float z3 = (d0 + 3 < n) ? cs * (c3 * dv.w) : -INFINITY;
        float zc = fmaxf(fmaxf(z0, z1), fmaxf(z2, z3));
        float r = __expf(fminf(m - zc, 0.f));   // min kills -inf-(-inf)=NaN
        se *= r; sp *= r; m = fmaxf(m, zc);
        float mm = fmaxf(m, -1e30f);            // keep finite for lanes w/o data
        float e0 = __expf(z0 - mm), e1 = __expf(z1 - mm);
        float e2 = __expf(z2 - mm), e3 = __expf(z3 - mm);
        se += (e0 + e1) + (e2 + e3);
        sp += e0 * c0 + e1 * c1 + e2 * c2 + e3 * c3;
    }
    // cross-lane merge of (m, se, sp)
    for (int o = 32; o; o >>= 1) {
        float mo = __shfl_xor(m, o);
        float so = __shfl_xor(se, o);
        float po = __shfl_xor(sp, o);
        float M = fmaxf(m, mo);
        float e1 = __expf(fminf(m - M, 0.f));
        float e2 = __expf(fminf(mo - M, 0.f));
        se = se * e1 + so * e2;
        sp = sp * e1 + po * e2;
        m = M;
    }
    if (lane == 0) A[(size_t)s * NQH + hg] = SQRT_HD * sp / se;
}

// ---- final = A @ M, tiled 16 rows x 256 cols per block ----
__global__ void k_out(const float* __restrict__ A, const float* __restrict__ M,
                      float* __restrict__ out, int S) {
    __shared__ float a[512];
    int tid = threadIdx.x;
    int s0 = blockIdx.y * 16;
    a[tid] = A[(size_t)s0 * NQH + tid];
    a[tid + 256] = A[(size_t)s0 * NQH + tid + 256];
    __syncthreads();
    int i = blockIdx.x * 256 + tid;
    float acc[16];
#pragma unroll
    for (int r = 0; r < 16; ++r) acc[r] = 0.f;
    for (int hg = 0; hg < NQH; ++hg) {
        float mv = M[(size_t)hg * HID + i];
#pragma unroll
        for (int r = 0; r < 16; ++r) acc[r] += a[r * NQH + hg] * mv;
    }
#pragma unroll
    for (int r = 0; r < 16; ++r)
        out[(size_t)(s0 + r) * HID + i] = acc[r];
}

extern "C" void kernel_launch(void* const* d_in, const int* in_sizes, int n_in,
                              void* d_out, int out_size, void* d_ws, size_t ws_size,
                              hipStream_t stream) {
    const int*   ids = (const int*)d_in[0];
    const float* Wq  = (const float*)d_in[2];
    const float* Wk  = (const float*)d_in[3];
    const float* Wv  = (const float*)d_in[4];
    const float* Wo  = (const float*)d_in[5];
    float* out = (float*)d_out;
    const int S = in_sizes[0];                      // B=1, S=2048

    // ws layout (floats unless noted):
    //  [Pq 64*4096 | Pk 64*1024 | Pv 64*1024]  (M[32*4096] aliases this region
    //                                           after k_red consumes partials)
    //  [Sq 4096][Sk 1024][Sv 1024][D 32*S][cp S][A 32*S][Tc 64*S f64][Ts 64*S f64]
    // cp must sit right after D: k_alpha reads cps[-dlt] (lands in D) and
    // float4 over-reads past D's end (land in cp, masked lanes).
    float* ws = (float*)d_ws;
    float* Pq = ws;
    float* Pk = Pq + (size_t)CH * NQH * HD;
    float* Pv = Pk + (size_t)CH * NKVH * HD;
    float* M  = ws;                                 // alias of partials
    float* Sq = Pv + (size_t)CH * NKVH * HD;
    float* Sk = Sq + HID;
    float* Sv = Sk + NKVH * HD;
    float* D  = Sv + NKVH * HD;
    float* cp = D + (size_t)NQH * S;
    float* A  = cp + S;
    double* Tc = (double*)(A + (size_t)NQH * S);
    double* Ts = Tc + (size_t)64 * S;

    int nxb = S >> 8;
    k_part<<<64 * nxb + 6 * CH, 256, 0, stream>>>(
        ids, Wq, Wk, Wv, Pq, Pk, Pv, cp, Tc, Ts, S);
    k_red<<<6, 256, 0, stream>>>(Pq, Pk, Pv, Sq, Sk, Sv);
    k_main<<<128 + NQH * nxb, 256, 0, stream>>>(Sq, Sk, Sv, Wo, Tc, Ts, M, D, S);
    k_alpha<<<S * 8, 256, 0, stream>>>(ids, cp, D, A, S);
    k_out<<<dim3(HID / 256, S / 16), 256, 0, stream>>>(A, M, out, S);
}

// Round 5
// 94.808 us; speedup vs baseline: 1.7887x; 1.1023x over previous
//
#include <hip/hip_runtime.h>
#include <math.h>

// ---------------------------------------------------------------------------
// RopeAttentionModel reduced form:
//   x[s,:] = c_s * ones(HID)  =>  q/k/v rank-1: c_s * colsum(W)
//   scores[s,hg,k] = c_s*c_k * D[hg, s-k] / sqrt(128)
//   D[hg,d] = sum_j P[hg,j]*cos(d*f_j) - Q[hg,j]*sin(d*f_j)   (f64)
//   alpha[s,hg] = softmax-weighted mean of c_k  (scalar per (s,head))
//   out = A[S,32] @ M[32,4096],  M[hg,:] = Sv[h] . Wo[hg*128:+128, :]
// No atomics. DAG: k_part -> k_red -> k_dtab -> k_fuse(M || alpha) -> k_out
// ---------------------------------------------------------------------------

#define HID 4096
#define NQH 32
#define NKVH 8
#define HD 128
#define CHQ 128                   // colsum chunks (32 rows each)
#define RSQRT_HD 0.08838834764831845f
#define SQRT_HD  11.313708498984761f
#define LOG2E    1.4426950408889634f

// partial column sum over 32 rows, 4 batches of 8 in-flight float4 loads
__device__ __forceinline__ void colsum_part32(const float* __restrict__ W,
                                              float* __restrict__ P,
                                              int cols4, int c4, int chunk) {
    const float4* b = reinterpret_cast<const float4*>(W);
    float ax = 0.f, ay = 0.f, az = 0.f, aw = 0.f;
#pragma unroll
    for (int bb = 0; bb < 4; ++bb) {
        size_t p = (size_t)(chunk * 32 + bb * 8) * cols4 + c4;
        float4 tt[8];
#pragma unroll
        for (int i = 0; i < 8; ++i) tt[i] = b[p + (size_t)i * cols4];
        ax += ((tt[0].x + tt[1].x) + (tt[2].x + tt[3].x)) +
              ((tt[4].x + tt[5].x) + (tt[6].x + tt[7].x));
        ay += ((tt[0].y + tt[1].y) + (tt[2].y + tt[3].y)) +
              ((tt[4].y + tt[5].y) + (tt[6].y + tt[7].y));
        az += ((tt[0].z + tt[1].z) + (tt[2].z + tt[3].z)) +
              ((tt[4].z + tt[5].z) + (tt[6].z + tt[7].z));
        aw += ((tt[0].w + tt[1].w) + (tt[2].w + tt[3].w)) +
              ((tt[4].w + tt[5].w) + (tt[6].w + tt[7].w));
    }
    reinterpret_cast<float4*>(P)[(size_t)chunk * cols4 + c4] =
        make_float4(ax, ay, az, aw);
}

// ---- fused: Wq/Wk/Wv partial colsums + trig table + cpsh copies ----
__global__ __launch_bounds__(256) void k_part(
        const int* __restrict__ ids,
        const float* __restrict__ Wq, const float* __restrict__ Wk,
        const float* __restrict__ Wv,
        float* __restrict__ Pq, float* __restrict__ Pk, float* __restrict__ Pv,
        float* __restrict__ cpsh, double* __restrict__ Tc,
        double* __restrict__ Ts, int S) {
    int t = blockIdx.x;
    int tid = threadIdx.x;
    int nxb = S >> 8;
    if (t < 4 * CHQ) {
        colsum_part32(Wq, Pq, NQH * HD / 4, (t & 3) * 256 + tid, t >> 2);
    } else if (t < 5 * CHQ) {
        colsum_part32(Wk, Pk, NKVH * HD / 4, tid, t - 4 * CHQ);
    } else if (t < 6 * CHQ) {
        colsum_part32(Wv, Pv, NKVH * HD / 4, tid, t - 5 * CHQ);
    } else if (t < 6 * CHQ + 64 * nxb) {
        int u = t - 6 * CHQ;
        int j = u / nxb, xb = u - j * nxb;
        int dlt = xb * 256 + tid;
        double f = (double)(float)(1.0 / pow(10000.0, (double)j / 64.0));
        double sv, cv;
        sincos((double)dlt * f, &sv, &cv);
        Tc[(size_t)j * S + dlt] = cv;
        Ts[(size_t)j * S + dlt] = sv;
    } else {
        // cpsh: 4 shifted copies, copy r at [r*LEN, (r+1)*LEN), LEN = S+768.
        // cpsh[r*LEN + pos] = cp[pos-384-r] (0 outside), cp[i] = ids[i]/sqrt(128)
        int u = t - 6 * CHQ - 64 * nxb;     // 0..15
        int r = u >> 2, seg = u & 3;
        int LEN = S + 768;
        for (int pos = seg * 256 + tid; pos < LEN; pos += 1024) {
            int i = pos - 384 - r;
            float v = (i >= 0 && i < S) ? (float)ids[i] * RSQRT_HD : 0.f;
            cpsh[(size_t)r * LEN + pos] = v;
        }
    }
}

// ---- reduce partials -> Sq, Sk, Sv (6 blocks) ----
__global__ __launch_bounds__(256) void k_red(
        const float* __restrict__ Pq, const float* __restrict__ Pk,
        const float* __restrict__ Pv, float* __restrict__ Sq,
        float* __restrict__ Sk, float* __restrict__ Sv) {
    int t = blockIdx.x;
    const float* P; float* Sd; int cols4, c4;
    if (t < 4)      { P = Pq; Sd = Sq; cols4 = NQH * HD / 4; c4 = t * 256 + threadIdx.x; }
    else if (t == 4){ P = Pk; Sd = Sk; cols4 = NKVH * HD / 4; c4 = threadIdx.x; }
    else            { P = Pv; Sd = Sv; cols4 = NKVH * HD / 4; c4 = threadIdx.x; }
    const float4* b = reinterpret_cast<const float4*>(P);
    float ax = 0.f, ay = 0.f, az = 0.f, aw = 0.f;
    for (int c = 0; c < CHQ; c += 8) {
        float4 tt[8];
#pragma unroll
        for (int i = 0; i < 8; ++i) tt[i] = b[(size_t)(c + i) * cols4 + c4];
        ax += ((tt[0].x + tt[1].x) + (tt[2].x + tt[3].x)) +
              ((tt[4].x + tt[5].x) + (tt[6].x + tt[7].x));
        ay += ((tt[0].y + tt[1].y) + (tt[2].y + tt[3].y)) +
              ((tt[4].y + tt[5].y) + (tt[6].y + tt[7].y));
        az += ((tt[0].z + tt[1].z) + (tt[2].z + tt[3].z)) +
              ((tt[4].z + tt[5].z) + (tt[6].z + tt[7].z));
        aw += ((tt[0].w + tt[1].w) + (tt[2].w + tt[3].w)) +
              ((tt[4].w + tt[5].w) + (tt[6].w + tt[7].w));
    }
    reinterpret_cast<float4*>(Sd)[c4] = make_float4(ax, ay, az, aw);
}

// ---- D table: [32][S], f64 accumulation over the shared trig table ----
__global__ __launch_bounds__(256) void k_dtab(
        const float* __restrict__ Sq, const float* __restrict__ Sk,
        const double* __restrict__ Tc, const double* __restrict__ Ts,
        float* __restrict__ D, int S) {
    __shared__ double p[64], q[64];
    int hg = blockIdx.y, h = hg >> 2;
    int tid = threadIdx.x;
    if (tid < 64) {
        double a1 = Sq[hg * HD + tid], a2 = Sq[hg * HD + tid + 64];
        double b1 = Sk[h * HD + tid],  b2 = Sk[h * HD + tid + 64];
        p[tid] = a1 * b1 + a2 * b2;
        q[tid] = a2 * b1 - a1 * b2;
    }
    __syncthreads();
    int dlt = blockIdx.x * 256 + tid;
    const double* tc = Tc + dlt;
    const double* ts = Ts + dlt;
    double acc = 0.0;
#pragma unroll 8
    for (int j = 0; j < 64; ++j)
        acc += p[j] * tc[(size_t)j * S] - q[j] * ts[(size_t)j * S];
    D[(size_t)hg * S + dlt] = (float)acc;
}

// ---- fused: M slabs (Sv.Wo, VMEM-bound) + alpha (VALU-bound) ----
__global__ __launch_bounds__(256) void k_fuse(
        const int* __restrict__ ids, const float* __restrict__ cpsh,
        const float* __restrict__ D, const float* __restrict__ Sv,
        const float* __restrict__ Wo, float* __restrict__ Mp,
        float* __restrict__ A, int S) {
    int t = blockIdx.x;
    int tid = threadIdx.x;
    if (t < 512) {
        // Mp[sl][hg][:] = Sv[h, sl*32:+32] . Wo[hg*128+sl*32 : +32, :]
        int sl = t & 3, x = (t >> 2) & 3, hg = t >> 4;
        int h = hg >> 2, dbase = hg * HD + sl * 32;
        int i4 = x * 256 + tid;
        const float4* b = reinterpret_cast<const float4*>(Wo);
        const float* sv = Sv + h * HD + sl * 32;
        float ax = 0.f, ay = 0.f, az = 0.f, aw = 0.f;
#pragma unroll
        for (int bb = 0; bb < 4; ++bb) {
            size_t p = (size_t)(dbase + bb * 8) * (HID / 4) + i4;
            float4 tt[8]; float ss[8];
#pragma unroll
            for (int i = 0; i < 8; ++i) { tt[i] = b[p + (size_t)i * (HID / 4)]; ss[i] = sv[bb * 8 + i]; }
#pragma unroll
            for (int i = 0; i < 8; ++i) {
                ax += ss[i] * tt[i].x; ay += ss[i] * tt[i].y;
                az += ss[i] * tt[i].z; aw += ss[i] * tt[i].w;
            }
        }
        reinterpret_cast<float4*>(Mp)[((size_t)sl * NQH + hg) * (HID / 4) + i4] =
            make_float4(ax, ay, az, aw);
        return;
    }
    // ---- alpha: one wave per (s,hg), online softmax in log2 domain ----
    int u = t - 512;
    int w = u * 4 + (tid >> 6);
    int lane = tid & 63;
    int s = S - 1 - (w >> 5);              // long rows first
    int hg = w & 31;
    float csl = (float)ids[s] * LOG2E;
    const float* Drow = D + (size_t)hg * S;
    int r = (3 - s) & 3;
    const float* cbase = cpsh + (size_t)r * (S + 768) + 384 + (s - 3 + r);
    // float4 at (cbase - d0) = { cp[s-d0-3], cp[s-d0-2], cp[s-d0-1], cp[s-d0] }

    float m = -INFINITY, se = 0.f, sp = 0.f;
    int n = s + 1;
    int nFull = n >> 8;
    int it = 0;
    for (; it + 2 <= nFull; it += 2) {     // 2 chunks, 4 loads in flight
        int d0 = it * 256 + lane * 4, d1 = d0 + 256;
        float4 dv0 = *reinterpret_cast<const float4*>(Drow + d0);
        float4 dv1 = *reinterpret_cast<const float4*>(Drow + d1);
        float4 cv0 = *reinterpret_cast<const float4*>(cbase - d0);
        float4 cv1 = *reinterpret_cast<const float4*>(cbase - d1);
        float z0 = csl * (cv0.w * dv0.x), z1 = csl * (cv0.z * dv0.y);
        float z2 = csl * (cv0.y * dv0.z), z3 = csl * (cv0.x * dv0.w);
        float z4 = csl * (cv1.w * dv1.x), z5 = csl * (cv1.z * dv1.y);
        float z6 = csl * (cv1.y * dv1.z), z7 = csl * (cv1.x * dv1.w);
        float zc = fmaxf(fmaxf(fmaxf(z0, z1), fmaxf(z2, z3)),
                         fmaxf(fmaxf(z4, z5), fmaxf(z6, z7)));
        if (!__all(zc <= m)) {             // wave-uniform deferred rescale
            float rr = __builtin_amdgcn_exp2f(fminf(m - zc, 0.f));
            se *= rr; sp *= rr; m = fmaxf(m, zc);
        }
        float e0 = __builtin_amdgcn_exp2f(z0 - m), e1 = __builtin_amdgcn_exp2f(z1 - m);
        float e2 = __builtin_amdgcn_exp2f(z2 - m), e3 = __builtin_amdgcn_exp2f(z3 - m);
        float e4 = __builtin_amdgcn_exp2f(z4 - m), e5 = __builtin_amdgcn_exp2f(z5 - m);
        float e6 = __builtin_amdgcn_exp2f(z6 - m), e7 = __builtin_amdgcn_exp2f(z7 - m);
        se += ((e0 + e1) + (e2 + e3)) + ((e4 + e5) + (e6 + e7));
        sp += ((e0 * cv0.w + e1 * cv0.z) + (e2 * cv0.y + e3 * cv0.x)) +
              ((e4 * cv1.w + e5 * cv1.z) + (e6 * cv1.y + e7 * cv1.x));
    }
    if (it < nFull) {                      // odd leftover full chunk
        int d0 = it * 256 + lane * 4;
        float4 dv0 = *reinterpret_cast<const float4*>(Drow + d0);
        float4 cv0 = *reinterpret_cast<const float4*>(cbase - d0);
        float z0 = csl * (cv0.w * dv0.x), z1 = csl * (cv0.z * dv0.y);
        float z2 = csl * (cv0.y * dv0.z), z3 = csl * (cv0.x * dv0.w);
        float zc = fmaxf(fmaxf(z0, z1), fmaxf(z2, z3));
        if (!__all(zc <= m)) {
            float rr = __builtin_amdgcn_exp2f(fminf(m - zc, 0.f));
            se *= rr; sp *= rr; m = fmaxf(m, zc);
        }
        float e0 = __builtin_amdgcn_exp2f(z0 - m), e1 = __builtin_amdgcn_exp2f(z1 - m);
        float e2 = __builtin_amdgcn_exp2f(z2 - m), e3 = __builtin_amdgcn_exp2f(z3 - m);
        se += (e0 + e1) + (e2 + e3);
        sp += (e0 * cv0.w + e1 * cv0.z) + (e2 * cv0.y + e3 * cv0.x);
    }
    if (n & 255) {                          // masked tail chunk
        int d0 = nFull * 256 + lane * 4;
        float4 dv0 = *reinterpret_cast<const float4*>(Drow + d0); // OOB reads finite
        float4 cv0 = *reinterpret_cast<const float4*>(cbase - d0); // pads are 0
        float z0 = (d0 + 0 < n) ? csl * (cv0.w * dv0.x) : -INFINITY;
        float z1 = (d0 + 1 < n) ? csl * (cv0.z * dv0.y) : -INFINITY;
        float z2 = (d0 + 2 < n) ? csl * (cv0.y * dv0.z) : -INFINITY;
        float z3 = (d0 + 3 < n) ? csl * (cv0.x * dv0.w) : -INFINITY;
        float zc = fmaxf(fmaxf(z0, z1), fmaxf(z2, z3));
        float rr = __builtin_amdgcn_exp2f(fminf(m - zc, 0.f)); // min kills inf-inf NaN
        se *= rr; sp *= rr; m = fmaxf(m, zc);
        float mm = fmaxf(m, -1e30f);        // finite for all-masked lanes
        float e0 = __builtin_amdgcn_exp2f(z0 - mm), e1 = __builtin_amdgcn_exp2f(z1 - mm);
        float e2 = __builtin_amdgcn_exp2f(z2 - mm), e3 = __builtin_amdgcn_exp2f(z3 - mm);
        se += (e0 + e1) + (e2 + e3);
        sp += (e0 * cv0.w + e1 * cv0.z) + (e2 * cv0.y + e3 * cv0.x);
    }
    // cross-lane merge of (m, se, sp)
    for (int o = 32; o; o >>= 1) {
        float mo = __shfl_xor(m, o);
        float so = __shfl_xor(se, o);
        float po = __shfl_xor(sp, o);
        float M2 = fmaxf(m, mo);
        float ea = __builtin_amdgcn_exp2f(fminf(m - M2, 0.f));
        float eb = __builtin_amdgcn_exp2f(fminf(mo - M2, 0.f));
        se = se * ea + so * eb;
        sp = sp * ea + po * eb;
        m = M2;
    }
    if (lane == 0) A[(size_t)s * NQH + hg] = SQRT_HD * sp / se;
}

// ---- final = A @ (sum of 4 M slabs), 16 rows x 256 cols per block ----
__global__ void k_out(const float* __restrict__ A, const float* __restrict__ Mp,
                      float* __restrict__ out, int S) {
    __shared__ float a[512];
    int tid = threadIdx.x;
    int s0 = blockIdx.y * 16;
    a[tid] = A[(size_t)s0 * NQH + tid];
    a[tid + 256] = A[(size_t)s0 * NQH + tid + 256];
    __syncthreads();
    int i = blockIdx.x * 256 + tid;
    float acc[16];
#pragma unroll
    for (int rr = 0; rr < 16; ++rr) acc[rr] = 0.f;
    for (int hg = 0; hg < NQH; ++hg) {
        float mv = Mp[(size_t)(0 * NQH + hg) * HID + i]
                 + Mp[(size_t)(1 * NQH + hg) * HID + i]
                 + Mp[(size_t)(2 * NQH + hg) * HID + i]
                 + Mp[(size_t)(3 * NQH + hg) * HID + i];
#pragma unroll
        for (int rr = 0; rr < 16; ++rr) acc[rr] += a[rr * NQH + hg] * mv;
    }
#pragma unroll
    for (int rr = 0; rr < 16; ++rr)
        out[(size_t)(s0 + rr) * HID + i] = acc[rr];
}

extern "C" void kernel_launch(void* const* d_in, const int* in_sizes, int n_in,
                              void* d_out, int out_size, void* d_ws, size_t ws_size,
                              hipStream_t stream) {
    const int*   ids = (const int*)d_in[0];
    const float* Wq  = (const float*)d_in[2];
    const float* Wk  = (const float*)d_in[3];
    const float* Wv  = (const float*)d_in[4];
    const float* Wo  = (const float*)d_in[5];
    float* out = (float*)d_out;
    const int S = in_sizes[0];                      // B=1, S=2048
    const int nxb = S >> 8;
    const int LEN = S + 768;

    // ws layout (floats unless noted):
    //  [Pq CHQ*4096 | Pk CHQ*1024 | Pv CHQ*1024]   (Mp[4*32*4096] aliases Pq
    //                                               after k_red consumes it)
    //  [Sq][Sk][Sv][D 32*S][A 32*S][cpsh 4*LEN][Tc 64*S f64][Ts 64*S f64]
    // D tail over-reads land in A (finite); cpsh pads are explicit zeros.
    float* ws = (float*)d_ws;
    float* Pq = ws;
    float* Pk = Pq + (size_t)CHQ * NQH * HD;
    float* Pv = Pk + (size_t)CHQ * NKVH * HD;
    float* Mp = Pq;                                 // alias (4*NQH*HID <= Pq size)
    float* Sq = Pv + (size_t)CHQ * NKVH * HD;
    float* Sk = Sq + HID;
    float* Sv = Sk + NKVH * HD;
    float* D  = Sv + NKVH * HD;
    float* A  = D + (size_t)NQH * S;
    float* cpsh = A + (size_t)NQH * S;
    double* Tc = (double*)(cpsh + 4 * (size_t)LEN);
    double* Ts = Tc + (size_t)64 * S;

    k_part<<<6 * CHQ + 64 * nxb + 16, 256, 0, stream>>>(
        ids, Wq, Wk, Wv, Pq, Pk, Pv, cpsh, Tc, Ts, S);
    k_red<<<6, 256, 0, stream>>>(Pq, Pk, Pv, Sq, Sk, Sv);
    k_dtab<<<dim3(nxb, NQH), 256, 0, stream>>>(Sq, Sk, Tc, Ts, D, S);
    k_fuse<<<512 + S * 8, 256, 0, stream>>>(ids, cpsh, D, Sv, Wo, Mp, A, S);
    k_out<<<dim3(HID / 256, S / 16), 256, 0, stream>>>(A, Mp, out, S);
}

// Round 6
// 84.665 us; speedup vs baseline: 2.0030x; 1.1198x over previous
//
#include <hip/hip_runtime.h>
#include <math.h>

// ---------------------------------------------------------------------------
// RopeAttentionModel reduced form:
//   x[s,:] = c_s * ones(HID)  =>  q/k/v rank-1: c_s * colsum(W)
//   scores[s,hg,k] = c_s*c_k * D[hg, s-k] / sqrt(128)
//   D[hg,d] = sum_j P[hg,j]*cos(d*f_j) - Q[hg,j]*sin(d*f_j)   (f64)
//   alpha[s,hg] = softmax-weighted mean of c_k  (scalar per (s,head))
//   out = A[S,32] @ M[32,4096],  M[hg,:] = Sv[h] . Wo[hg*128:+128, :]
// alpha: lane-per-row scan (coalesced D, uniform cp, no shfl merges).
// ---------------------------------------------------------------------------

#define HID 4096
#define NQH 32
#define NKVH 8
#define HD 128
#define CHQ 128                   // colsum chunks (32 rows each)
#define TS 64                     // s-rows per alpha block (one per lane)
#define RSQRT_HD 0.08838834764831845f
#define LOG2E    1.4426950408889634f

// partial column sum over 32 rows, 4 batches of 8 in-flight float4 loads
__device__ __forceinline__ void colsum_part32(const float* __restrict__ W,
                                              float* __restrict__ P,
                                              int cols4, int c4, int chunk) {
    const float4* b = reinterpret_cast<const float4*>(W);
    float ax = 0.f, ay = 0.f, az = 0.f, aw = 0.f;
#pragma unroll
    for (int bb = 0; bb < 4; ++bb) {
        size_t p = (size_t)(chunk * 32 + bb * 8) * cols4 + c4;
        float4 tt[8];
#pragma unroll
        for (int i = 0; i < 8; ++i) tt[i] = b[p + (size_t)i * cols4];
        ax += ((tt[0].x + tt[1].x) + (tt[2].x + tt[3].x)) +
              ((tt[4].x + tt[5].x) + (tt[6].x + tt[7].x));
        ay += ((tt[0].y + tt[1].y) + (tt[2].y + tt[3].y)) +
              ((tt[4].y + tt[5].y) + (tt[6].y + tt[7].y));
        az += ((tt[0].z + tt[1].z) + (tt[2].z + tt[3].z)) +
              ((tt[4].z + tt[5].z) + (tt[6].z + tt[7].z));
        aw += ((tt[0].w + tt[1].w) + (tt[2].w + tt[3].w)) +
              ((tt[4].w + tt[5].w) + (tt[6].w + tt[7].w));
    }
    reinterpret_cast<float4*>(P)[(size_t)chunk * cols4 + c4] =
        make_float4(ax, ay, az, aw);
}

// ---- fused: Wq/Wk/Wv partial colsums + trig table + cp ----
__global__ __launch_bounds__(256) void k_part(
        const int* __restrict__ ids,
        const float* __restrict__ Wq, const float* __restrict__ Wk,
        const float* __restrict__ Wv,
        float* __restrict__ Pq, float* __restrict__ Pk, float* __restrict__ Pv,
        float* __restrict__ cp, double* __restrict__ Tc,
        double* __restrict__ Ts, int S) {
    int t = blockIdx.x;
    int tid = threadIdx.x;
    int nxb = S >> 8;
    if (t < 4 * CHQ) {
        colsum_part32(Wq, Pq, NQH * HD / 4, (t & 3) * 256 + tid, t >> 2);
    } else if (t < 5 * CHQ) {
        colsum_part32(Wk, Pk, NKVH * HD / 4, tid, t - 4 * CHQ);
    } else if (t < 6 * CHQ) {
        colsum_part32(Wv, Pv, NKVH * HD / 4, tid, t - 5 * CHQ);
    } else {
        int u = t - 6 * CHQ;
        int j = u / nxb, xb = u - j * nxb;
        int dlt = xb * 256 + tid;
        double f = (double)(float)(1.0 / pow(10000.0, (double)j / 64.0));
        double sv, cv;
        sincos((double)dlt * f, &sv, &cv);
        Tc[(size_t)j * S + dlt] = cv;
        Ts[(size_t)j * S + dlt] = sv;
        if (j == 0) cp[dlt] = (float)ids[dlt];
    }
}

// ---- reduce partials -> Sq, Sk, Sv (6 blocks) ----
__global__ __launch_bounds__(256) void k_red(
        const float* __restrict__ Pq, const float* __restrict__ Pk,
        const float* __restrict__ Pv, float* __restrict__ Sq,
        float* __restrict__ Sk, float* __restrict__ Sv) {
    int t = blockIdx.x;
    const float* P; float* Sd; int cols4, c4;
    if (t < 4)      { P = Pq; Sd = Sq; cols4 = NQH * HD / 4; c4 = t * 256 + threadIdx.x; }
    else if (t == 4){ P = Pk; Sd = Sk; cols4 = NKVH * HD / 4; c4 = threadIdx.x; }
    else            { P = Pv; Sd = Sv; cols4 = NKVH * HD / 4; c4 = threadIdx.x; }
    const float4* b = reinterpret_cast<const float4*>(P);
    float ax = 0.f, ay = 0.f, az = 0.f, aw = 0.f;
    for (int c = 0; c < CHQ; c += 8) {
        float4 tt[8];
#pragma unroll
        for (int i = 0; i < 8; ++i) tt[i] = b[(size_t)(c + i) * cols4 + c4];
        ax += ((tt[0].x + tt[1].x) + (tt[2].x + tt[3].x)) +
              ((tt[4].x + tt[5].x) + (tt[6].x + tt[7].x));
        ay += ((tt[0].y + tt[1].y) + (tt[2].y + tt[3].y)) +
              ((tt[4].y + tt[5].y) + (tt[6].y + tt[7].y));
        az += ((tt[0].z + tt[1].z) + (tt[2].z + tt[3].z)) +
              ((tt[4].z + tt[5].z) + (tt[6].z + tt[7].z));
        aw += ((tt[0].w + tt[1].w) + (tt[2].w + tt[3].w)) +
              ((tt[4].w + tt[5].w) + (tt[6].w + tt[7].w));
    }
    reinterpret_cast<float4*>(Sd)[c4] = make_float4(ax, ay, az, aw);
}

// ---- fused: M slabs (Sv.Wo, VMEM-bound) + D table (f64 from trig) ----
__global__ __launch_bounds__(256) void k_mid(
        const float* __restrict__ Sq, const float* __restrict__ Sk,
        const float* __restrict__ Sv, const float* __restrict__ Wo,
        const double* __restrict__ Tc, const double* __restrict__ Ts,
        float* __restrict__ Mp, float* __restrict__ D, int S) {
    int t = blockIdx.x;
    int tid = threadIdx.x;
    if (t < 512) {
        // Mp[sl][hg][:] = Sv[h, sl*32:+32] . Wo[hg*128+sl*32 : +32, :]
        int sl = t & 3, x = (t >> 2) & 3, hg = t >> 4;
        int h = hg >> 2, dbase = hg * HD + sl * 32;
        int i4 = x * 256 + tid;
        const float4* b = reinterpret_cast<const float4*>(Wo);
        const float* sv = Sv + h * HD + sl * 32;
        float ax = 0.f, ay = 0.f, az = 0.f, aw = 0.f;
#pragma unroll
        for (int bb = 0; bb < 4; ++bb) {
            size_t p = (size_t)(dbase + bb * 8) * (HID / 4) + i4;
            float4 tt[8]; float ss[8];
#pragma unroll
            for (int i = 0; i < 8; ++i) { tt[i] = b[p + (size_t)i * (HID / 4)]; ss[i] = sv[bb * 8 + i]; }
#pragma unroll
            for (int i = 0; i < 8; ++i) {
                ax += ss[i] * tt[i].x; ay += ss[i] * tt[i].y;
                az += ss[i] * tt[i].z; aw += ss[i] * tt[i].w;
            }
        }
        reinterpret_cast<float4*>(Mp)[((size_t)sl * NQH + hg) * (HID / 4) + i4] =
            make_float4(ax, ay, az, aw);
    } else {
        // D[hg, dlt] = sum_j p[j]*cos - q[j]*sin   (f64)
        __shared__ double p[64], q[64];
        int u = t - 512;
        int nxb = S >> 8;
        int hg = u / nxb, xb = u - hg * nxb, h = hg >> 2;
        if (tid < 64) {
            double a1 = Sq[hg * HD + tid], a2 = Sq[hg * HD + tid + 64];
            double b1 = Sk[h * HD + tid],  b2 = Sk[h * HD + tid + 64];
            p[tid] = a1 * b1 + a2 * b2;
            q[tid] = a2 * b1 - a1 * b2;
        }
        __syncthreads();
        int dlt = xb * 256 + tid;
        const double* tc = Tc + dlt;
        const double* ts = Ts + dlt;
        double acc = 0.0;
#pragma unroll 8
        for (int j = 0; j < 64; ++j)
            acc += p[j] * tc[(size_t)j * S] - q[j] * ts[(size_t)j * S];
        D[(size_t)hg * S + dlt] = (float)acc;
    }
}

// ---- alpha: lane-per-row. Block = (hg, 64-row tile); 4 waves split k. ----
// Also: last 16 blocks reduce Mp (4 slabs) -> M.
__global__ __launch_bounds__(256) void k_alpha(
        const int* __restrict__ ids, const float* __restrict__ cp,
        const float* __restrict__ D, const float* __restrict__ Mp,
        float* __restrict__ M, float* __restrict__ A, int S) {
    int t = blockIdx.x;
    int tid = threadIdx.x;
    int nAlpha = (S / TS) * NQH;
    if (t >= nAlpha) {
        // Mp[4][NQH][HID] -> M[NQH][HID]
        int u = t - nAlpha;
        const float4* mp = reinterpret_cast<const float4*>(Mp);
        float4* m4 = reinterpret_cast<float4*>(M);
        const int Q = NQH * HID / 4;
        for (int j = u * 256 + tid; j < Q; j += 16 * 256) {
            float4 a = mp[j], b = mp[j + Q], c = mp[j + 2 * Q], d = mp[j + 3 * Q];
            m4[j] = make_float4(a.x + b.x + c.x + d.x, a.y + b.y + c.y + d.y,
                                a.z + b.z + c.z + d.z, a.w + b.w + c.w + d.w);
        }
        return;
    }
    int tile = t >> 5;                 // 0.. S/64-1, longest rows first
    int hg = t & 31;
    int s0 = S - TS - tile * TS;
    int w = tid >> 6, lane = tid & 63;
    int sl = s0 + lane;                // this lane's row
    float csl = (float)ids[sl] * (RSQRT_HD * LOG2E);   // >= 0
    const float* Drow = D + (size_t)hg * S + sl;       // Drow[-k] = D[hg][sl-k]

    int n = s0 + TS;                   // max row length in tile
    int q4 = ((n + 15) >> 4) << 2;     // per-wave k quota, multiple of 4
    int k = w * q4;
    int k1 = (k + q4 < n) ? k + q4 : n;
    int lim = (k1 < s0 + 1) ? k1 : s0 + 1;   // fully-valid bound

    float tm = -1e30f;                 // running max of t = cp_k * D
    float mz = csl * tm;               // running max in log2-score units
    float se = 0.f, sp = 0.f;

    // fast loop: 2 chunks (8 k) per iter, all lanes valid
    for (; k + 8 <= lim; k += 8) {
        float4 cv0 = *reinterpret_cast<const float4*>(cp + k);
        float4 cv1 = *reinterpret_cast<const float4*>(cp + k + 4);
        float d0 = Drow[-k],     d1 = Drow[-(k+1)], d2 = Drow[-(k+2)], d3 = Drow[-(k+3)];
        float d4 = Drow[-(k+4)], d5 = Drow[-(k+5)], d6 = Drow[-(k+6)], d7 = Drow[-(k+7)];
        float t0 = cv0.x * d0, t1 = cv0.y * d1, t2 = cv0.z * d2, t3 = cv0.w * d3;
        float t4 = cv1.x * d4, t5 = cv1.y * d5, t6 = cv1.z * d6, t7 = cv1.w * d7;
        float m8 = fmaxf(fmaxf(fmaxf(t0, t1), fmaxf(t2, t3)),
                         fmaxf(fmaxf(t4, t5), fmaxf(t6, t7)));
        if (!__all(m8 <= tm)) {
            float ntm = fmaxf(tm, m8);
            float nmz = csl * ntm;
            float r = __builtin_amdgcn_exp2f(fminf(mz - nmz, 0.f));
            se *= r; sp *= r; tm = ntm; mz = nmz;
        }
        float e0 = __builtin_amdgcn_exp2f(fmaf(csl, t0, -mz));
        float e1 = __builtin_amdgcn_exp2f(fmaf(csl, t1, -mz));
        float e2 = __builtin_amdgcn_exp2f(fmaf(csl, t2, -mz));
        float e3 = __builtin_amdgcn_exp2f(fmaf(csl, t3, -mz));
        float e4 = __builtin_amdgcn_exp2f(fmaf(csl, t4, -mz));
        float e5 = __builtin_amdgcn_exp2f(fmaf(csl, t5, -mz));
        float e6 = __builtin_amdgcn_exp2f(fmaf(csl, t6, -mz));
        float e7 = __builtin_amdgcn_exp2f(fmaf(csl, t7, -mz));
        se += ((e0 + e1) + (e2 + e3)) + ((e4 + e5) + (e6 + e7));
        sp = fmaf(e0, cv0.x, sp); sp = fmaf(e1, cv0.y, sp);
        sp = fmaf(e2, cv0.z, sp); sp = fmaf(e3, cv0.w, sp);
        sp = fmaf(e4, cv1.x, sp); sp = fmaf(e5, cv1.y, sp);
        sp = fmaf(e6, cv1.z, sp); sp = fmaf(e7, cv1.w, sp);
    }
    for (; k + 4 <= lim; k += 4) {     // leftover full chunk
        float4 cv = *reinterpret_cast<const float4*>(cp + k);
        float d0 = Drow[-k], d1 = Drow[-(k+1)], d2 = Drow[-(k+2)], d3 = Drow[-(k+3)];
        float t0 = cv.x * d0, t1 = cv.y * d1, t2 = cv.z * d2, t3 = cv.w * d3;
        float m4 = fmaxf(fmaxf(t0, t1), fmaxf(t2, t3));
        if (!__all(m4 <= tm)) {
            float ntm = fmaxf(tm, m4);
            float nmz = csl * ntm;
            float r = __builtin_amdgcn_exp2f(fminf(mz - nmz, 0.f));
            se *= r; sp *= r; tm = ntm; mz = nmz;
        }
        float e0 = __builtin_amdgcn_exp2f(fmaf(csl, t0, -mz));
        float e1 = __builtin_amdgcn_exp2f(fmaf(csl, t1, -mz));
        float e2 = __builtin_amdgcn_exp2f(fmaf(csl, t2, -mz));
        float e3 = __builtin_amdgcn_exp2f(fmaf(csl, t3, -mz));
        se += (e0 + e1) + (e2 + e3);
        sp = fmaf(e0, cv.x, sp); sp = fmaf(e1, cv.y, sp);
        sp = fmaf(e2, cv.z, sp); sp = fmaf(e3, cv.w, sp);
    }
    // masked tail chunks (lane-dependent validity; k stays 4-aligned)
    for (; k < k1; k += 4) {
        float4 cv = *reinterpret_cast<const float4*>(cp + k);  // tiny over-read ok
        float d0 = Drow[-k], d1 = Drow[-(k+1)], d2 = Drow[-(k+2)], d3 = Drow[-(k+3)];
        bool v0 = (k + 0 <= sl) && (k + 0 < k1);
        bool v1 = (k + 1 <= sl) && (k + 1 < k1);
        bool v2 = (k + 2 <= sl) && (k + 2 < k1);
        bool v3 = (k + 3 <= sl) && (k + 3 < k1);
        float t0 = v0 ? cv.x * d0 : -1e30f;
        float t1 = v1 ? cv.y * d1 : -1e30f;
        float t2 = v2 ? cv.z * d2 : -1e30f;
        float t3 = v3 ? cv.w * d3 : -1e30f;
        float m4 = fmaxf(fmaxf(t0, t1), fmaxf(t2, t3));
        if (!__all(m4 <= tm)) {
            float ntm = fmaxf(tm, m4);
            float nmz = csl * ntm;
            float r = __builtin_amdgcn_exp2f(fminf(mz - nmz, 0.f));
            se *= r; sp *= r; tm = ntm; mz = nmz;
        }
        float e0 = __builtin_amdgcn_exp2f(fmaf(csl, t0, -mz)); e0 = v0 ? e0 : 0.f;
        float e1 = __builtin_amdgcn_exp2f(fmaf(csl, t1, -mz)); e1 = v1 ? e1 : 0.f;
        float e2 = __builtin_amdgcn_exp2f(fmaf(csl, t2, -mz)); e2 = v2 ? e2 : 0.f;
        float e3 = __builtin_amdgcn_exp2f(fmaf(csl, t3, -mz)); e3 = v3 ? e3 : 0.f;
        se += (e0 + e1) + (e2 + e3);
        sp = fmaf(e0, cv.x, sp); sp = fmaf(e1, cv.y, sp);
        sp = fmaf(e2, cv.z, sp); sp = fmaf(e3, cv.w, sp);
    }

    // 4-way merge across waves via LDS (per row)
    __shared__ float lm[4][TS], ls[4][TS], lp[4][TS];
    lm[w][lane] = mz; ls[w][lane] = se; lp[w][lane] = sp;
    __syncthreads();
    if (tid < TS) {
        float m0 = lm[0][tid], m1 = lm[1][tid], m2 = lm[2][tid], m3 = lm[3][tid];
        float mm = fmaxf(fmaxf(m0, m1), fmaxf(m2, m3));
        float r0 = __builtin_amdgcn_exp2f(fminf(m0 - mm, 0.f));
        float r1 = __builtin_amdgcn_exp2f(fminf(m1 - mm, 0.f));
        float r2 = __builtin_amdgcn_exp2f(fminf(m2 - mm, 0.f));
        float r3 = __builtin_amdgcn_exp2f(fminf(m3 - mm, 0.f));
        float seT = ls[0][tid] * r0 + ls[1][tid] * r1 + ls[2][tid] * r2 + ls[3][tid] * r3;
        float spT = lp[0][tid] * r0 + lp[1][tid] * r1 + lp[2][tid] * r2 + lp[3][tid] * r3;
        A[(size_t)hg * S + s0 + tid] = spT / seT;
    }
}

// ---- final: out[s,:] = sum_hg A[hg][s] * M[hg][:] ----
__global__ void k_out(const float* __restrict__ A, const float* __restrict__ M,
                      float* __restrict__ out, int S) {
    __shared__ float a[512];                       // [16 rows][32 hg]
    int tid = threadIdx.x;
    int s0 = blockIdx.y * 16;
    for (int v = tid; v < 512; v += 256) {
        int hg = v >> 4, r = v & 15;
        a[r * NQH + hg] = A[(size_t)hg * S + s0 + r];
    }
    __syncthreads();
    int i = blockIdx.x * 256 + tid;
    float acc[16];
#pragma unroll
    for (int rr = 0; rr < 16; ++rr) acc[rr] = 0.f;
    for (int hg = 0; hg < NQH; ++hg) {
        float mv = M[(size_t)hg * HID + i];
#pragma unroll
        for (int rr = 0; rr < 16; ++rr) acc[rr] += a[rr * NQH + hg] * mv;
    }
#pragma unroll
    for (int rr = 0; rr < 16; ++rr)
        out[(size_t)(s0 + rr) * HID + i] = acc[rr];
}

extern "C" void kernel_launch(void* const* d_in, const int* in_sizes, int n_in,
                              void* d_out, int out_size, void* d_ws, size_t ws_size,
                              hipStream_t stream) {
    const int*   ids = (const int*)d_in[0];
    const float* Wq  = (const float*)d_in[2];
    const float* Wk  = (const float*)d_in[3];
    const float* Wv  = (const float*)d_in[4];
    const float* Wo  = (const float*)d_in[5];
    float* out = (float*)d_out;
    const int S = in_sizes[0];                      // B=1, S=2048
    const int nxb = S >> 8;

    // ws layout (floats unless noted):
    //  [Pq CHQ*4096 | Pk CHQ*1024 | Pv CHQ*1024]  (Mp[4][32][4096] aliases Pq)
    //  [Sq][Sk][Sv][D 32*S][cp S][A 32*S][M 32*4096][Tc 64*S f64][Ts 64*S f64]
    // D negative over-reads land in Sq/Sk/Sv (finite); cp over-reads land in A
    // (finite, masked out).
    float* ws = (float*)d_ws;
    float* Pq = ws;
    float* Pk = Pq + (size_t)CHQ * NQH * HD;
    float* Pv = Pk + (size_t)CHQ * NKVH * HD;
    float* Mp = Pq;                                 // alias
    float* Sq = Pv + (size_t)CHQ * NKVH * HD;
    float* Sk = Sq + HID;
    float* Sv = Sk + NKVH * HD;
    float* D  = Sv + NKVH * HD;
    float* cp = D + (size_t)NQH * S;
    float* A  = cp + S;
    float* M  = A + (size_t)NQH * S;
    double* Tc = (double*)(M + (size_t)NQH * HID);
    double* Ts = Tc + (size_t)64 * S;

    k_part<<<6 * CHQ + 64 * nxb, 256, 0, stream>>>(
        ids, Wq, Wk, Wv, Pq, Pk, Pv, cp, Tc, Ts, S);
    k_red<<<6, 256, 0, stream>>>(Pq, Pk, Pv, Sq, Sk, Sv);
    k_mid<<<512 + NQH * nxb, 256, 0, stream>>>(Sq, Sk, Sv, Wo, Tc, Ts, Mp, D, S);
    k_alpha<<<(S / TS) * NQH + 16, 256, 0, stream>>>(ids, cp, D, Mp, M, A, S);
    k_out<<<dim3(HID / 256, S / 16), 256, 0, stream>>>(A, M, out, S);
}